// Round 8
// baseline (567.110 us; speedup 1.0000x reference)
//
#include <hip/hip_runtime.h>

typedef __bf16 bf16;
typedef __attribute__((ext_vector_type(8))) __bf16 bf16x8;
typedef __attribute__((ext_vector_type(4))) float f32x4;
typedef __attribute__((ext_vector_type(4))) short s16x4;

#define HDIM 2048
#define LDST 36   // padded LDS row stride (elems): 18 dwords -> ~2-way banks

__device__ __forceinline__ void glds16(const void* g, void* l) {
  __builtin_amdgcn_global_load_lds((const __attribute__((address_space(1))) void*)g,
                                   (__attribute__((address_space(3))) void*)l,
                                   16, 0, 0);
}

#define MFMA16(a, b, c) __builtin_amdgcn_mfma_f32_16x16x32_bf16(a, b, c, 0, 0, 0)

// fp32 -> bf16 bulk convert: grid (1024, 5).
__global__ __launch_bounds__(256) void cvt5(
    const float* __restrict__ s0, const float* __restrict__ s1,
    const float* __restrict__ s2, const float* __restrict__ s3,
    const float* __restrict__ s4,
    bf16* __restrict__ d0, bf16* __restrict__ d1, bf16* __restrict__ d2,
    bf16* __restrict__ d3, bf16* __restrict__ d4) {
  const float* s; bf16* d;
  switch (blockIdx.y) {
    case 0: s = s0; d = d0; break;
    case 1: s = s1; d = d1; break;
    case 2: s = s2; d = d2; break;
    case 3: s = s3; d = d3; break;
    default: s = s4; d = d4; break;
  }
  const size_t base = (size_t)blockIdx.x * 4096 + (threadIdx.x << 2);
  for (int i = 0; i < 4; i++) {
    const float4 v = *(const float4*)(s + base + i * 1024);
    union { bf16 h[4]; s16x4 s4v; } u;
    u.h[0] = (bf16)v.x; u.h[1] = (bf16)v.y; u.h[2] = (bf16)v.z; u.h[3] = (bf16)v.w;
    *(s16x4*)(d + base + i * 1024) = u.s4v;
  }
}

// acc[4][4] = A[rowBase:+128,:] @ B[colBase:+128,:]^T, bf16 row-major.
// Reg-staged, padded (stride 36), double-buffered, 1 barrier/iter.
// Coalesced global (64B/quad) + ~conflict-free LDS on both write and read.
__device__ __forceinline__ void gemm128_db(const bf16* __restrict__ A,
                                           const bf16* __restrict__ B,
                                           int rowBase, int colBase,
                                           f32x4 acc[4][4],
                                           bf16* ldsA, bf16* ldsB) {
  const int t = threadIdx.x, w = t >> 6, l = t & 63;
  const int wr = (w >> 1) << 6, wc = (w & 1) << 6;
  const int lr = l & 15, lq = l >> 4;
  const int sr = l >> 2, sc = (l & 3) << 3;   // 4 lanes/row: 64B contiguous/quad
  const int BUF = 128 * LDST;

  const bf16* gA0 = A + (size_t)(rowBase + w * 32 + sr) * HDIM + sc;
  const bf16* gA1 = gA0 + (size_t)16 * HDIM;
  const bf16* gB0 = B + (size_t)(colBase + w * 32 + sr) * HDIM + sc;
  const bf16* gB1 = gB0 + (size_t)16 * HDIM;
  const int wo0 = (w * 32 + sr) * LDST + sc;
  const int wo1 = wo0 + 16 * LDST;

  for (int mi = 0; mi < 4; mi++)
    for (int ni = 0; ni < 4; ni++)
      for (int r = 0; r < 4; r++) acc[mi][ni][r] = 0.f;

  // prologue: stage iter 0 into buf 0
  bf16x8 ra0 = *(const bf16x8*)gA0, ra1 = *(const bf16x8*)gA1;
  bf16x8 rb0 = *(const bf16x8*)gB0, rb1 = *(const bf16x8*)gB1;
  gA0 += 32; gA1 += 32; gB0 += 32; gB1 += 32;
  *(bf16x8*)&ldsA[wo0] = ra0; *(bf16x8*)&ldsA[wo1] = ra1;
  *(bf16x8*)&ldsB[wo0] = rb0; *(bf16x8*)&ldsB[wo1] = rb1;
  __syncthreads();

  int p = 0;
  for (int k = 0; k < 64; k++) {
    if (k < 63) {   // prefetch next K-slice into regs (no LDS dependence)
      ra0 = *(const bf16x8*)gA0; ra1 = *(const bf16x8*)gA1;
      rb0 = *(const bf16x8*)gB0; rb1 = *(const bf16x8*)gB1;
      gA0 += 32; gA1 += 32; gB0 += 32; gB1 += 32;
    }
    const bf16* bufA = ldsA + p * BUF;
    const bf16* bufB = ldsB + p * BUF;
    bf16x8 af[4], bfr[4];
    for (int mi = 0; mi < 4; mi++)
      af[mi] = *(const bf16x8*)&bufA[(wr + mi * 16 + lr) * LDST + lq * 8];
    for (int ni = 0; ni < 4; ni++)
      bfr[ni] = *(const bf16x8*)&bufB[(wc + ni * 16 + lr) * LDST + lq * 8];
    for (int mi = 0; mi < 4; mi++)
      for (int ni = 0; ni < 4; ni++)
        acc[mi][ni] = MFMA16(af[mi], bfr[ni], acc[mi][ni]);
    if (k < 63) {   // write prefetched slice to the other buffer
      bf16* dA = ldsA + (p ^ 1) * BUF;
      bf16* dB = ldsB + (p ^ 1) * BUF;
      *(bf16x8*)&dA[wo0] = ra0; *(bf16x8*)&dA[wo1] = ra1;
      *(bf16x8*)&dB[wo0] = rb0; *(bf16x8*)&dB[wo1] = rb1;
    }
    __syncthreads();
    p ^= 1;
  }
}

// z=0: q = hs@Wq^T (normal [B,H])
// z=1: Kf frag-major: frag ((h*16+kbk)*32 + ni*4+ks):
//      key = kbk*128+ni*16+(lane&15), dim = h*128+ks*32+(lane>>4)*8+j
// z=2: Vf frag-major: dim = h*128+ni*16+(lane&15), key = kbk*128+ks*32+(lane>>4)*8+j
__global__ __launch_bounds__(256) void qkv_gemm(
    const bf16* __restrict__ hs, const bf16* __restrict__ Wq,
    const bf16* __restrict__ Wk, const bf16* __restrict__ Wv,
    bf16* __restrict__ qb, bf16* __restrict__ Kf, bf16* __restrict__ Vf) {
  __shared__ bf16 ldsA[2 * 128 * LDST];
  __shared__ bf16 ldsB[2 * 128 * LDST];
  const int z = blockIdx.z;
  const bf16* W = (z == 0) ? Wq : (z == 1) ? Wk : Wv;
  const int rowBase = blockIdx.y << 7, colBase = blockIdx.x << 7;
  f32x4 acc[4][4];
  gemm128_db(hs, W, rowBase, colBase, acc, ldsA, ldsB);

  const int t = threadIdx.x;
  const int w = t >> 6, l = t & 63;
  const int wr = (w >> 1) << 6, wc = (w & 1) << 6;
  const int lr = l & 15, lq = l >> 4;

  if (z == 0) {
    for (int mi = 0; mi < 4; mi++)
      for (int ni = 0; ni < 4; ni++) {
        const int col = colBase + wc + ni * 16 + lr;
        const int row0 = rowBase + wr + mi * 16 + lq * 4;
        for (int r = 0; r < 4; r++)
          qb[(size_t)(row0 + r) * HDIM + col] = (bf16)acc[mi][ni][r];
      }
  } else if (z == 1) {
    for (int mi = 0; mi < 4; mi++)
      for (int ni = 0; ni < 4; ni++) {
        const int dim = colBase + wc + ni * 16 + lr;
        const int hh = dim >> 7, ks = (dim >> 5) & 3, kh = (dim >> 3) & 3, j = dim & 7;
        const int row0 = rowBase + wr + mi * 16 + lq * 4;
        for (int r = 0; r < 4; r++) {
          const int key = row0 + r;
          const int kbk = key >> 7, kni = (key >> 4) & 7, kl = key & 15;
          Kf[(((size_t)hh * 16 + kbk) * 32 + kni * 4 + ks) * 512 +
             (kh * 16 + kl) * 8 + j] = (bf16)acc[mi][ni][r];
        }
      }
  } else {
    for (int mi = 0; mi < 4; mi++)
      for (int ni = 0; ni < 4; ni++) {
        const int dim = colBase + wc + ni * 16 + lr;
        const int hh = dim >> 7, vni = (dim >> 4) & 7, ll = dim & 15;
        const int row0 = rowBase + wr + mi * 16 + lq * 4;
        const int kbk = row0 >> 7, ks = (row0 >> 5) & 3, lh = (row0 >> 3) & 3;
        const int j0 = row0 & 7;
        union { bf16 h4[4]; s16x4 v; } u;
        for (int r = 0; r < 4; r++) u.h4[r] = (bf16)acc[mi][ni][r];
        *(s16x4*)&Vf[(((size_t)hh * 16 + kbk) * 32 + vni * 4 + ks) * 512 +
                     (lh * 16 + ll) * 8 + j0] = u.v;
      }
  }
}

// Flash attention v6 (unchanged from r7 — passed, conflicts 0).
__global__ __launch_bounds__(256, 2) void attn_kernel(
    const bf16* __restrict__ qb, const bf16* __restrict__ Kf,
    const bf16* __restrict__ Vf, const unsigned char* __restrict__ amask,
    bf16* __restrict__ ctx) {
  __shared__ bf16 Kl[32 * 512];
  __shared__ bf16 Vl[32 * 512];
  __shared__ bf16 Pl[4 * 2048];

  const int qt = blockIdx.x, h = blockIdx.y;
  const int t = threadIdx.x, w = t >> 6, l = t & 63;
  const int lr = l & 15, lq = l >> 4;
  const int wq = w & 1, wk = w >> 1;
  bf16* Pw = Pl + (w << 11);

  bf16x8 aq[2][4];
  for (int mi = 0; mi < 2; mi++)
    for (int ks = 0; ks < 4; ks++)
      aq[mi][ks] = *(const bf16x8*)&qb[(size_t)(qt * 64 + wq * 32 + mi * 16 + lr) * HDIM +
                                       h * 128 + ks * 32 + lq * 8];

  f32x4 o[2][8];
  for (int mi = 0; mi < 2; mi++)
    for (int ni = 0; ni < 8; ni++)
      for (int r = 0; r < 4; r++) o[mi][ni][r] = 0.f;
  float lsum[2] = {0.f, 0.f};

  const float c = 0.08838834764831845f * 1.4426950408889634f;
  const int lr7 = lr & 7;

  for (int kbk = 0; kbk < 16; kbk++) {
    const size_t tileOff = ((size_t)h * 16 + kbk) * 32 * 512;

    for (int i = 0; i < 8; i++) {
      const int frag = i * 4 + w;
      glds16(Kf + tileOff + frag * 512 + l * 8, Kl + frag * 512);
    }
    bf16x8 vtmp[8];
    for (int i = 0; i < 8; i++)
      vtmp[i] = *(const bf16x8*)&Vf[tileOff + (i * 4 + w) * 512 + l * 8];
    for (int i = 0; i < 8; i++)
      *(bf16x8*)&Vl[(i * 4 + w) * 512 + l * 8] = vtmp[i];
    __syncthreads();

    f32x4 s[2][4];
    for (int mi = 0; mi < 2; mi++)
      for (int ni = 0; ni < 4; ni++)
        for (int r = 0; r < 4; r++) s[mi][ni][r] = 0.f;
    for (int ks = 0; ks < 4; ks++) {
      bf16x8 bk[4];
      for (int ni = 0; ni < 4; ni++)
        bk[ni] = *(const bf16x8*)&Kl[((wk * 4 + ni) * 4 + ks) * 512 + l * 8];
      for (int mi = 0; mi < 2; mi++)
        for (int ni = 0; ni < 4; ni++)
          s[mi][ni] = MFMA16(bk[ni], aq[mi][ks], s[mi][ni]);
    }

    const bool dblk = (((kbk << 1) | wk) == qt);
    for (int ni = 0; ni < 4; ni++) {
      const int kbase = kbk * 128 + wk * 64 + ni * 16 + lq * 4;
      const unsigned mword = *(const unsigned*)&amask[kbase];
      for (int mi = 0; mi < 2; mi++) {
        const int qrowg = qt * 64 + wq * 32 + mi * 16 + lr;
        for (int r = 0; r < 4; r++) {
          float p = __builtin_exp2f(s[mi][ni][r] * c);
          if (!((mword >> (8 * r)) & 0xffu)) p = 0.f;
          if (dblk && (kbase + r == qrowg)) p = 0.f;
          s[mi][ni][r] = p;
          lsum[mi] += p;
        }
      }
    }

    for (int mi = 0; mi < 2; mi++)
      for (int ni = 0; ni < 4; ni++) {
        union { bf16 h4[4]; s16x4 v; } u;
        for (int r = 0; r < 4; r++) u.h4[r] = (bf16)s[mi][ni][r];
        const int row = mi * 16 + lr;
        const int g = ((ni * 2 + (lq >> 1)) ^ lr7);
        *(s16x4*)&Pw[row * 64 + (g << 3) + ((lq & 1) << 2)] = u.v;
      }

    for (int ks2 = 0; ks2 < 2; ks2++) {
      bf16x8 ap[2];
      for (int mi = 0; mi < 2; mi++)
        ap[mi] = *(const bf16x8*)&Pw[(mi * 16 + lr) * 64 +
                                     (((ks2 * 4 + lq) ^ lr7) << 3)];
      for (int ni = 0; ni < 8; ni++) {
        const bf16x8 bv = *(const bf16x8*)&Vl[(ni * 4 + wk * 2 + ks2) * 512 + l * 8];
        for (int mi = 0; mi < 2; mi++)
          o[mi][ni] = MFMA16(ap[mi], bv, o[mi][ni]);
      }
    }
    __syncthreads();
  }

  for (int mi = 0; mi < 2; mi++) {
    lsum[mi] += __shfl_xor(lsum[mi], 16);
    lsum[mi] += __shfl_xor(lsum[mi], 32);
  }

  float* Ocomb = (float*)Kl;
  float* Ls = (float*)Vl;
  if (wk == 1) {
    f32x4* dst = (f32x4*)Ocomb + wq * 1024;
    for (int i = 0; i < 16; i++) dst[i * 64 + l] = o[i >> 3][i & 7];
    if (lq == 0) {
      Ls[wq * 32 + lr] = lsum[0];
      Ls[wq * 32 + 16 + lr] = lsum[1];
    }
  }
  __syncthreads();
  if (wk == 0) {
    const f32x4* src = (const f32x4*)Ocomb + wq * 1024;
    for (int i = 0; i < 16; i++) {
      const f32x4 v = src[i * 64 + l];
      for (int r = 0; r < 4; r++) o[i >> 3][i & 7][r] += v[r];
    }
    lsum[0] += Ls[wq * 32 + lr];
    lsum[1] += Ls[wq * 32 + 16 + lr];
    Ls[64 + wq * 32 + lr] = lsum[0];
    Ls[64 + wq * 32 + 16 + lr] = lsum[1];
  }
  __syncthreads();
  if (wk == 0) {
    for (int mi = 0; mi < 2; mi++)
      for (int r = 0; r < 4; r++) {
        const float li = Ls[64 + wq * 32 + mi * 16 + lq * 4 + r];
        const int row = qt * 64 + wq * 32 + mi * 16 + lq * 4 + r;
        for (int ni = 0; ni < 8; ni++) {
          const float val = (li > 0.f) ? o[mi][ni][r] / li : 0.f;
          ctx[(size_t)row * HDIM + h * 128 + ni * 16 + lr] = (bf16)val;
        }
      }
  }
}

// out = fp32( hs + sigmoid(scale) * (ctx @ Wo^T) ), 128x64 tiles, reg-staged
// padded double-buffered core (A: 2 loads/wave, B: 1 load/wave).
__global__ __launch_bounds__(256) void out_gemm(
    const bf16* __restrict__ ctx, const bf16* __restrict__ Wo,
    const float* __restrict__ hs, const float* __restrict__ scale_p,
    float* __restrict__ outp) {
  __shared__ bf16 ldsA[2 * 128 * LDST];
  __shared__ bf16 ldsB[2 * 64 * LDST];
  const int rowBase = blockIdx.y << 7, colBase = blockIdx.x << 6;
  const int t = threadIdx.x, w = t >> 6, l = t & 63;
  const int wr = (w >> 1) << 6, wc = (w & 1) << 5;
  const int lr = l & 15, lq = l >> 4;
  const int sr = l >> 2, sc = (l & 3) << 3;
  const int BUFA = 128 * LDST, BUFB = 64 * LDST;

  const bf16* gA0 = ctx + (size_t)(rowBase + w * 32 + sr) * HDIM + sc;
  const bf16* gA1 = gA0 + (size_t)16 * HDIM;
  const bf16* gB0 = Wo + (size_t)(colBase + w * 16 + sr) * HDIM + sc;
  const int woA0 = (w * 32 + sr) * LDST + sc;
  const int woA1 = woA0 + 16 * LDST;
  const int woB = (w * 16 + sr) * LDST + sc;

  f32x4 acc[4][2];
  for (int mi = 0; mi < 4; mi++)
    for (int ni = 0; ni < 2; ni++)
      for (int r = 0; r < 4; r++) acc[mi][ni][r] = 0.f;

  bf16x8 ra0 = *(const bf16x8*)gA0, ra1 = *(const bf16x8*)gA1;
  bf16x8 rb0 = *(const bf16x8*)gB0;
  gA0 += 32; gA1 += 32; gB0 += 32;
  *(bf16x8*)&ldsA[woA0] = ra0; *(bf16x8*)&ldsA[woA1] = ra1;
  *(bf16x8*)&ldsB[woB] = rb0;
  __syncthreads();

  int p = 0;
  for (int k = 0; k < 64; k++) {
    if (k < 63) {
      ra0 = *(const bf16x8*)gA0; ra1 = *(const bf16x8*)gA1;
      rb0 = *(const bf16x8*)gB0;
      gA0 += 32; gA1 += 32; gB0 += 32;
    }
    const bf16* bufA = ldsA + p * BUFA;
    const bf16* bufB = ldsB + p * BUFB;
    bf16x8 af[4], bfr[2];
    for (int mi = 0; mi < 4; mi++)
      af[mi] = *(const bf16x8*)&bufA[(wr + mi * 16 + lr) * LDST + lq * 8];
    for (int ni = 0; ni < 2; ni++)
      bfr[ni] = *(const bf16x8*)&bufB[(wc + ni * 16 + lr) * LDST + lq * 8];
    for (int mi = 0; mi < 4; mi++)
      for (int ni = 0; ni < 2; ni++)
        acc[mi][ni] = MFMA16(af[mi], bfr[ni], acc[mi][ni]);
    if (k < 63) {
      bf16* dA = ldsA + (p ^ 1) * BUFA;
      bf16* dB = ldsB + (p ^ 1) * BUFB;
      *(bf16x8*)&dA[woA0] = ra0; *(bf16x8*)&dA[woA1] = ra1;
      *(bf16x8*)&dB[woB] = rb0;
    }
    __syncthreads();
    p ^= 1;
  }

  const float sig = 1.0f / (1.0f + __expf(-scale_p[0]));
  for (int mi = 0; mi < 4; mi++)
    for (int ni = 0; ni < 2; ni++) {
      const int col = colBase + wc + ni * 16 + lr;
      const int row0 = rowBase + wr + mi * 16 + lq * 4;
      for (int r = 0; r < 4; r++) {
        const size_t idx = (size_t)(row0 + r) * HDIM + col;
        outp[idx] = hs[idx] + sig * acc[mi][ni][r];
      }
    }
}

extern "C" void kernel_launch(void* const* d_in, const int* in_sizes, int n_in,
                              void* d_out, int out_size, void* d_ws, size_t ws_size,
                              hipStream_t stream) {
  const float* hs = (const float*)d_in[0];
  const unsigned char* amask = (const unsigned char*)d_in[1];
  const float* Wq = (const float*)d_in[2];
  const float* Wk = (const float*)d_in[3];
  const float* Wv = (const float*)d_in[4];
  const float* Wo = (const float*)d_in[5];
  const float* scale_p = (const float*)d_in[6];
  float* outp = (float*)d_out;

  const size_t N = (size_t)HDIM * HDIM;
  bf16* qb   = (bf16*)d_ws;
  bf16* Kf   = qb + N;
  bf16* Vf   = Kf + N;
  bf16* ctx  = Vf + N;
  bf16* hs16 = ctx + N;
  bf16* Wq16 = hs16 + N;
  bf16* Wk16 = Wq16 + N;
  bf16* Wv16 = Wk16 + N;
  bf16* Wo16 = Wv16 + N;   // 72 MB of d_ws

  cvt5<<<dim3(1024, 5), 256, 0, stream>>>(hs, Wq, Wk, Wv, Wo,
                                          hs16, Wq16, Wk16, Wv16, Wo16);
  qkv_gemm<<<dim3(16, 16, 3), 256, 0, stream>>>(hs16, Wq16, Wk16, Wv16, qb, Kf, Vf);
  attn_kernel<<<dim3(32, 16), 256, 0, stream>>>(qb, Kf, Vf, amask, ctx);
  out_gemm<<<dim3(32, 16), 256, 0, stream>>>(ctx, Wo16, hs, scale_p, outp);
}